// Round 7
// baseline (472.932 us; speedup 1.0000x reference)
//
#include <hip/hip_runtime.h>
#include <hip/hip_bf16.h>
#include <stdint.h>

typedef __hip_bfloat16 bf16;
typedef __attribute__((ext_vector_type(8))) short bf16x8;   // 8 bf16 = 4 VGPRs (MFMA A/B frag)
typedef __attribute__((ext_vector_type(4))) float f32x4;    // MFMA C/D frag

#define CC 1024
#define TT 2048
#define BB 4
#define BT 8192     // BB*TT
#define HH 16
#define NN 64       // head size

#define MFMA(a, b, c) __builtin_amdgcn_mfma_f32_16x16x32_bf16(a, b, c, 0, 0, 0)

// async global->LDS, 16B per lane. Direct addrspace casts (addrspacecast),
// NOT via uintptr_t (inttoptr of flat addr -> garbage LDS offset -> fault).
#define GLD(g, l) __builtin_amdgcn_global_load_lds( \
    (const __attribute__((address_space(1))) void*)(g), \
    (__attribute__((address_space(3))) void*)(l), 16, 0, 0)

__device__ __forceinline__ short f2bs(float f) {
    bf16 h = __float2bfloat16(f);
    return *reinterpret_cast<short*>(&h);
}
__device__ __forceinline__ float bs2f(short s) {
    bf16 h = *reinterpret_cast<bf16*>(&s);
    return __bfloat162float(h);
}

// ---------------------------------------------------------------------------
// 128x128 MFMA GEMM core, BK=32 (m97 structure; measured better than BK=64:
// r6 A/B — BK=64 dropped MfmaUtil 18.5->16.6, occupancy 29->26).
// ---------------------------------------------------------------------------
template <typename EPI>
__device__ __forceinline__ void gemm128(short* As, short* Bs,
                                        const bf16* __restrict__ A, int lda,
                                        const bf16* __restrict__ Bt, int ldb,
                                        int kiters, int m0, int n0, EPI epi)
{
    const int tid = threadIdx.x;
    const int l   = tid & 63, wv = tid >> 6;
    const int wm  = wv >> 1, wn = wv & 1;
    const int q   = l >> 4, lr = l & 15;
    const int row = tid & 127, kg1 = tid >> 7;

    f32x4 acc[4][4] = {};

    const bf16* ga = A  + (size_t)(m0 + row) * lda + kg1 * 8;
    const bf16* gb = Bt + (size_t)(n0 + row) * ldb + kg1 * 8;
    short* la1 = As + tid * 8;
    short* la2 = As + (tid + 256) * 8;
    short* lb1 = Bs + tid * 8;
    short* lb2 = Bs + (tid + 256) * 8;

    for (int kb = 0; kb < kiters; ++kb) {
        __syncthreads();
        const bf16* gak = ga + kb * 32;
        const bf16* gbk = gb + kb * 32;
        GLD(gak,      la1);
        GLD(gak + 16, la2);
        GLD(gbk,      lb1);
        GLD(gbk + 16, lb2);
        __syncthreads();
        bf16x8 af[4], bfb[4];
#pragma unroll
        for (int mt = 0; mt < 4; ++mt)
            af[mt] = *(const bf16x8*)(As + (q * 128 + wm * 64 + mt * 16 + lr) * 8);
#pragma unroll
        for (int nt = 0; nt < 4; ++nt)
            bfb[nt] = *(const bf16x8*)(Bs + (q * 128 + wn * 64 + nt * 16 + lr) * 8);
#pragma unroll
        for (int mt = 0; mt < 4; ++mt)
#pragma unroll
            for (int nt = 0; nt < 4; ++nt)
                acc[mt][nt] = MFMA(af[mt], bfb[nt], acc[mt][nt]);
    }
#pragma unroll
    for (int mt = 0; mt < 4; ++mt)
#pragma unroll
        for (int nt = 0; nt < 4; ++nt)
#pragma unroll
            for (int rr = 0; rr < 4; ++rr)
                epi(m0 + wm * 64 + mt * 16 + q * 4 + rr,
                    n0 + wn * 64 + nt * 16 + lr, acc[mt][nt][rr]);
}

// ---------------------------------------------------------------------------
// ALL prep in one launch: 13092 blocks.
//   [0,4096)  Wr/Wk/Wv/Wo -> bf16 transpose
//   [4096,4352) maa_w1 -> w1T (pad 256)   [4352,4480) gate_w1 -> w1T2[0]
//   [4480,4608) decay_w1 -> w1T2[1]       [4608,4672) gate_w2 -> w2T2[0]
//   [4672,4736) decay_w2 -> w2T2[1]       [4736,4896) maa_w2[f] -> w2T5[f]
//   [4896,4900) maas pack                 [4900,13092) xxx/xb/xxb elementwise
// ---------------------------------------------------------------------------
__global__ __launch_bounds__(256) void k_prep_all(
    const float* __restrict__ Wr, const float* __restrict__ Wk,
    const float* __restrict__ Wv, const float* __restrict__ Wo,
    const float* __restrict__ maa_w1, const float* __restrict__ gate_w1,
    const float* __restrict__ decay_w1, const float* __restrict__ gate_w2,
    const float* __restrict__ decay_w2, const float* __restrict__ maa_w2,
    const float* __restrict__ mw, const float* __restrict__ mk,
    const float* __restrict__ mv, const float* __restrict__ mr,
    const float* __restrict__ mg, const float* __restrict__ x,
    const float* __restrict__ maa_x,
    bf16* __restrict__ WT3, bf16* __restrict__ WoT, bf16* __restrict__ w1T,
    bf16* __restrict__ w1T2, bf16* __restrict__ w2T2, bf16* __restrict__ w2T5,
    float* __restrict__ maas, bf16* __restrict__ xxx,
    bf16* __restrict__ xb, bf16* __restrict__ xxb)
{
    __shared__ float tile[32][33];
    int idx = blockIdx.x;
    if (idx >= 4900) {                       // xb=x, xxb=shift(x)-x, xxx=x+xx*maa_x
        size_t i = ((size_t)(idx - 4900) * 256 + threadIdx.x) * 4;
        int cc = i & (CC - 1);
        int t  = (i >> 10) & (TT - 1);
        float4 xm = *(const float4*)(x + i);
        float4 xp = t ? *(const float4*)(x + i - CC)
                      : make_float4(0.f, 0.f, 0.f, 0.f);
        float4 ax = *(const float4*)(maa_x + cc);
        float xxv[4] = {xp.x - xm.x, xp.y - xm.y, xp.z - xm.z, xp.w - xm.w};
        float xmv[4] = {xm.x, xm.y, xm.z, xm.w};
        float axv[4] = {ax.x, ax.y, ax.z, ax.w};
#pragma unroll
        for (int e = 0; e < 4; ++e) {
            xb[i + e]  = __float2bfloat16(xmv[e]);
            xxb[i + e] = __float2bfloat16(xxv[e]);
            xxx[i + e] = __float2bfloat16(xmv[e] + xxv[e] * axv[e]);
        }
        return;
    }
    const float* src; bf16* dst; int rows, cols_in, tx_;
    if (idx < 4096) {
        int s = idx >> 10; idx &= 1023;
        src = (s == 0) ? Wr : (s == 1) ? Wk : (s == 2) ? Wv : Wo;
        dst = (s == 3) ? WoT : WT3 + (size_t)s * CC * CC;
        rows = CC; cols_in = CC; tx_ = 32;
    } else if (idx < 4352) { idx -= 4096; src = maa_w1;  dst = w1T;  rows = CC; cols_in = 160; tx_ = 8; }
    else if (idx < 4480)   { idx -= 4352; src = gate_w1; dst = w1T2; rows = CC; cols_in = 64;  tx_ = 4; }
    else if (idx < 4608)   { idx -= 4480; src = decay_w1; dst = w1T2 + 128 * CC; rows = CC; cols_in = 64; tx_ = 4; }
    else if (idx < 4672)   { idx -= 4608; src = gate_w2;  dst = w2T2;           rows = 64; cols_in = CC; tx_ = 32; }
    else if (idx < 4736)   { idx -= 4672; src = decay_w2; dst = w2T2 + CC * 64; rows = 64; cols_in = CC; tx_ = 32; }
    else if (idx < 4896)   { idx -= 4736; int f = idx >> 5; idx &= 31;
                             src = maa_w2 + (size_t)f * 32 * CC;
                             dst = w2T5 + (size_t)f * CC * 32; rows = 32; cols_in = CC; tx_ = 32; }
    else {
        int i = (idx - 4896) * 256 + threadIdx.x;
        if (i < CC) {
            maas[i]          = mw[i];
            maas[CC + i]     = mk[i];
            maas[2 * CC + i] = mv[i];
            maas[3 * CC + i] = mr[i];
            maas[4 * CC + i] = mg[i];
        }
        return;
    }
    int bx = idx % tx_, by = idx / tx_;
    int c0 = bx * 32, r0 = by * 32;
    int tx = threadIdx.x & 31, ty = threadIdx.x >> 5;
    for (int i = ty; i < 32; i += 8) {
        int cc2 = c0 + tx;
        tile[i][tx] = (cc2 < cols_in) ? src[(size_t)(r0 + i) * cols_in + cc2] : 0.f;
    }
    __syncthreads();
    for (int i = ty; i < 32; i += 8)
        dst[(size_t)(c0 + i) * rows + r0 + tx] = __float2bfloat16(tile[tx][i]);
}

__global__ __launch_bounds__(256) void g_lora(const bf16* __restrict__ xxx,
                                              const bf16* __restrict__ w1T,
                                              bf16* __restrict__ L)
{
    __shared__ __align__(16) short lds[8192];
    int m0 = blockIdx.x * 128, n0 = blockIdx.y * 128;
    gemm128(lds, lds + 4096, xxx, CC, w1T, CC, CC / 32, m0, n0,
            [&](int m, int n, float v) {
                if (n < 160) L[(size_t)m * 160 + n] = __float2bfloat16(tanhf(v));
            });
}

// All 5 xvars in one block (f inner loop; xb/xxb bf16 -> half epilogue bytes)
__global__ __launch_bounds__(256) void g_xvar(const bf16* __restrict__ L,
                                              const bf16* __restrict__ w2T,
                                              const float* __restrict__ maas,
                                              const bf16* __restrict__ xb,
                                              const bf16* __restrict__ xxb,
                                              bf16* __restrict__ xvars)
{
    __shared__ __align__(16) short lds[8192];
    int m0 = blockIdx.x * 128, n0 = blockIdx.y * 128;
    for (int f = 0; f < 5; ++f) {
        const bf16* A  = L + f * 32;
        const bf16* Bt = w2T + (size_t)f * CC * 32;
        const float* maa = maas + f * CC;
        bf16* out = xvars + (size_t)f * BT * CC;
        gemm128(lds, lds + 4096, A, 160, Bt, 32, 1, m0, n0,
                [&](int m, int n, float v) {
                    float xm = __bfloat162float(xb[(size_t)m * CC + n]);
                    float xx = __bfloat162float(xxb[(size_t)m * CC + n]);
                    out[(size_t)m * CC + n] =
                        __float2bfloat16(xm + xx * (maa[n] + v));
                });
    }
}

// ---------------------------------------------------------------------------
// r/k/v GEMMs (z=0,1,2) + gate/decay hidden GEMMs (z=3,4) in one dispatch.
// BK=32 core. z>=3 only needs blockIdx.y==0 (N=128 covers padded width).
// ---------------------------------------------------------------------------
__global__ __launch_bounds__(256) void g_rkv5(const bf16* __restrict__ xvars,
                                              const bf16* __restrict__ WT,
                                              const bf16* __restrict__ w1T2,
                                              bf16* __restrict__ rkv,
                                              bf16* __restrict__ hid)
{
    __shared__ __align__(16) short lds[8192];
    int z = blockIdx.z;
    int m0 = blockIdx.x * 128, n0 = blockIdx.y * 128;
    if (z < 3) {
        int f = (z == 0) ? 3 : z;              // r<-xr(f3), k<-xk(f1), v<-xv(f2)
        const bf16* A  = xvars + (size_t)f * BT * CC;
        const bf16* Bt = WT + (size_t)z * CC * CC;
        bf16* out = rkv + (size_t)z * BT * CC;
        gemm128(lds, lds + 4096, A, CC, Bt, CC, CC / 32, m0, n0,
                [&](int m, int n, float v) {
                    out[(size_t)m * CC + n] = __float2bfloat16(v);
                });
    } else {
        if (blockIdx.y != 0) return;
        int zz = z - 3;                        // 0=gate(f4), 1=decay(f0)
        const bf16* A  = xvars + (size_t)(zz == 0 ? 4 : 0) * BT * CC;
        const bf16* Bt = w1T2 + (size_t)zz * 128 * CC;
        bf16* out = hid + (size_t)zz * BT * 64;
        gemm128(lds, lds + 4096, A, CC, Bt, CC, CC / 32, m0, 0,
                [&](int m, int n, float v) {
                    if (n < 64) out[(size_t)m * 64 + n] = __float2bfloat16(tanhf(v));
                });
    }
}

// ---------------------------------------------------------------------------
// Chunk-parallel WKV6, pass 1: grid 2048 = (bh,chunk), 256 thr / 4 waves.
// Computes its own logw tile: lw[t][j] = -exp(td[ch] + hid_w[t]·w2dec[ch]).
// Then: prefix-scan; build RT,KT,KH,VT; A=tril(RT.KT^T)+diag;
// Y_local = A.V (bf16 out); M = VT.KH^T (bf16 out); RT persisted; pl out.
// ---------------------------------------------------------------------------
__global__ __launch_bounds__(256) void k_wkv_p1(const bf16* __restrict__ r,
                                                const bf16* __restrict__ kk,
                                                const bf16* __restrict__ vv,
                                                const bf16* __restrict__ hidW,
                                                const bf16* __restrict__ w2d,
                                                const float* __restrict__ td,
                                                const float* __restrict__ u,
                                                bf16* __restrict__ y,
                                                bf16* __restrict__ RTg,
                                                short* __restrict__ Mg,
                                                float* __restrict__ plg)
{
    constexpr int PW = 65, PB = 72;
    __shared__ __align__(16) char smem[16640 + 3 * 9216 + 768];
    float* LW = (float*)smem;                          // [64][65] fp32 scan
    short* VT = (short*)smem;                          // [64][72] bf16 (overlay)
    short* RT = (short*)(smem + 16640);                // [64][72]
    short* KT = (short*)(smem + 16640 + 9216);         // [64][72]
    short* AT = KT;                                    // overlay after MFMA1
    short* KH = (short*)(smem + 16640 + 2 * 9216);     // [64][72]
    short* HT = KT;                                    // hid_w staging (pre-C)
    short* WD = KH;                                    // w2dec staging (pre-C)
    float* SU = (float*)(smem + 16640 + 3 * 9216);
    float* SD = SU + 64;

    const int tid = threadIdx.x;
    const int lane = tid & 63, wq = tid >> 6;
    const int row = tid >> 2, g = tid & 3, j0 = g * 16;
    const int l15 = lane & 15, q = lane >> 4;
    const int bh = blockIdx.x >> 5, c = blockIdx.x & 31;
    const int b = bh >> 4, h = bh & 15;
    const size_t base = (size_t)b * TT * CC + (size_t)h * NN;
    const int t0 = c * 64;
    const int bt0 = b * TT + t0;
    const size_t cb = (size_t)blockIdx.x * 4096;       // [bh][c] 64x64 tile base

    if (tid < 64) SU[tid] = u[h * NN + tid];

    // ---- phase A0: stage hid_w tile [64t][64k] and w2dec slice [64ch][64k]
#pragma unroll
    for (int rnd = 0; rnd < 2; ++rnd) {
        int ee = rnd * 256 + tid;
        int rw = ee >> 3, c8 = (ee & 7) * 8;
        *(bf16x8*)(HT + rw * PB + c8) =
            *(const bf16x8*)(hidW + (size_t)(bt0 + rw) * 64 + c8);
        *(bf16x8*)(WD + rw * PB + c8) =
            *(const bf16x8*)(w2d + (size_t)(h * 64 + rw) * 64 + c8);
    }
    // r,k,v loads in flight during the lw MFMA
    const size_t gb = base + (size_t)(t0 + row) * CC + j0;
    bf16x8 r0 = *(const bf16x8*)(r + gb),  r1 = *(const bf16x8*)(r + gb + 8);
    bf16x8 k0 = *(const bf16x8*)(kk + gb), k1 = *(const bf16x8*)(kk + gb + 8);
    bf16x8 v0 = *(const bf16x8*)(vv + gb), v1 = *(const bf16x8*)(vv + gb + 8);
    float tdv[4];
#pragma unroll
    for (int ct = 0; ct < 4; ++ct) tdv[ct] = td[h * 64 + ct * 16 + l15];
    __syncthreads();
    // ---- phase A1: lw tile = hid_w @ w2dec^T ; lw = -exp(td + .)
    {
        bf16x8 aH0 = *(const bf16x8*)(HT + (wq * 16 + l15) * PB + q * 8);
        bf16x8 aH1 = *(const bf16x8*)(HT + (wq * 16 + l15) * PB + q * 8 + 32);
        f32x4 lwa[4] = {};
#pragma unroll
        for (int ct = 0; ct < 4; ++ct) {
            bf16x8 bW0 = *(const bf16x8*)(WD + (ct * 16 + l15) * PB + q * 8);
            bf16x8 bW1 = *(const bf16x8*)(WD + (ct * 16 + l15) * PB + q * 8 + 32);
            lwa[ct] = MFMA(aH0, bW0, lwa[ct]);
            lwa[ct] = MFMA(aH1, bW1, lwa[ct]);
        }
#pragma unroll
        for (int ct = 0; ct < 4; ++ct)
#pragma unroll
            for (int rr = 0; rr < 4; ++rr) {
                int t = wq * 16 + q * 4 + rr, j = ct * 16 + l15;
                LW[t * PW + j] = -expf(tdv[ct] + lwa[ct][rr]);
            }
    }
    __syncthreads();   // LW ready for scan; HT/WD reads done (phase C reuses)
    // ---- phase B: inclusive prefix-sum over t (lane=t), per channel j
    for (int jj = 0; jj < 16; ++jj) {
        int j = wq * 16 + jj;
        float xv = LW[lane * PW + j];
#pragma unroll
        for (int d = 1; d < 64; d <<= 1) {
            float t2 = __shfl_up(xv, d);
            if (lane >= d) xv += t2;
        }
        LW[lane * PW + j] = xv;
    }
    __syncthreads();
    // ---- phase C: build RT, KT, KH, diag, pl
    float rF[16], kF[16];
#pragma unroll
    for (int c2 = 0; c2 < 8; ++c2) {
        rF[c2] = bs2f(r0[c2]); rF[8 + c2] = bs2f(r1[c2]);
        kF[c2] = bs2f(k0[c2]); kF[8 + c2] = bs2f(k1[c2]);
    }
    float cwp[16], cwm[16], cwL[16];
#pragma unroll
    for (int c2 = 0; c2 < 16; ++c2) {
        cwp[c2] = LW[row * PW + j0 + c2];
        cwm[c2] = row ? LW[(row - 1) * PW + j0 + c2] : 0.f;
        cwL[c2] = LW[63 * PW + j0 + c2];
    }
    bf16x8 w0, w1;
#pragma unroll
    for (int c2 = 0; c2 < 8; ++c2) {
        w0[c2] = f2bs(rF[c2] * expf(cwm[c2]));
        w1[c2] = f2bs(rF[8 + c2] * expf(cwm[8 + c2]));
    }
    *(bf16x8*)(RT + row * PB + j0)     = w0;
    *(bf16x8*)(RT + row * PB + j0 + 8) = w1;
    *(bf16x8*)((short*)RTg + cb + row * 64 + j0)     = w0;   // persist for p3
    *(bf16x8*)((short*)RTg + cb + row * 64 + j0 + 8) = w1;
#pragma unroll
    for (int c2 = 0; c2 < 8; ++c2) {
        w0[c2] = f2bs(kF[c2] * expf(-cwp[c2]));
        w1[c2] = f2bs(kF[8 + c2] * expf(-cwp[8 + c2]));
    }
    *(bf16x8*)(KT + row * PB + j0)     = w0;
    *(bf16x8*)(KT + row * PB + j0 + 8) = w1;
#pragma unroll
    for (int c2 = 0; c2 < 16; ++c2)
        KH[(j0 + c2) * PB + row] = f2bs(kF[c2] * expf(cwL[c2] - cwp[c2]));
    if (tid < 64) plg[(size_t)blockIdx.x * 64 + tid] = expf(LW[63 * PW + tid]);
    float dpart = 0.f;
#pragma unroll
    for (int c2 = 0; c2 < 16; ++c2)
        dpart = fmaf(rF[c2] * kF[c2], SU[j0 + c2], dpart);
    dpart += __shfl_xor(dpart, 1);
    dpart += __shfl_xor(dpart, 2);
    if (g == 0) SD[row] = dpart;
    __syncthreads();
    // ---- phase D: VT writes (into dead LW region) + MFMA1 A = RT.KT^T
#pragma unroll
    for (int c2 = 0; c2 < 8; ++c2) {
        VT[(j0 + c2) * PB + row]     = v0[c2];
        VT[(j0 + 8 + c2) * PB + row] = v1[c2];
    }
    bf16x8 aF0 = *(const bf16x8*)(RT + (wq * 16 + l15) * PB + q * 8);
    bf16x8 aF1 = *(const bf16x8*)(RT + (wq * 16 + l15) * PB + q * 8 + 32);
    f32x4 Am[4] = {};
#pragma unroll
    for (int ct = 0; ct < 4; ++ct) {
        bf16x8 bF0 = *(const bf16x8*)(KT + (ct * 16 + l15) * PB + q * 8);
        bf16x8 bF1 = *(const bf16x8*)(KT + (ct * 16 + l15) * PB + q * 8 + 32);
        Am[ct] = MFMA(aF0, bF0, Am[ct]);
        Am[ct] = MFMA(aF1, bF1, Am[ct]);
    }
    __syncthreads();                 // KT reads done -> AT may overlay
#pragma unroll
    for (int ct = 0; ct < 4; ++ct)
#pragma unroll
        for (int rr = 0; rr < 4; ++rr) {
            int s = wq * 16 + q * 4 + rr, p = ct * 16 + l15;
            float vA = Am[ct][rr];
            vA = (p > s) ? 0.f : (p == s ? SD[s] : vA);
            AT[s * PB + p] = f2bs(vA);
        }
    __syncthreads();
    // ---- phase E: Y_local = A.V ; M = VT.KH^T
    f32x4 Y[4] = {}, M[4] = {};
    bf16x8 aA0 = *(const bf16x8*)(AT + (wq * 16 + l15) * PB + q * 8);
    bf16x8 aA1 = *(const bf16x8*)(AT + (wq * 16 + l15) * PB + q * 8 + 32);
    bf16x8 aV0 = *(const bf16x8*)(VT + (wq * 16 + l15) * PB + q * 8);
    bf16x8 aV1 = *(const bf16x8*)(VT + (wq * 16 + l15) * PB + q * 8 + 32);
#pragma unroll
    for (int ct = 0; ct < 4; ++ct) {
        bf16x8 bV0 = *(const bf16x8*)(VT + (ct * 16 + l15) * PB + q * 8);
        bf16x8 bV1 = *(const bf16x8*)(VT + (ct * 16 + l15) * PB + q * 8 + 32);
        Y[ct] = MFMA(aA0, bV0, Y[ct]);
        Y[ct] = MFMA(aA1, bV1, Y[ct]);
        bf16x8 bK0 = *(const bf16x8*)(KH + (ct * 16 + l15) * PB + q * 8);
        bf16x8 bK1 = *(const bf16x8*)(KH + (ct * 16 + l15) * PB + q * 8 + 32);
        M[ct] = MFMA(aV0, bK0, M[ct]);
        M[ct] = MFMA(aV1, bK1, M[ct]);
    }
#pragma unroll
    for (int ct = 0; ct < 4; ++ct)
#pragma unroll
        for (int rr = 0; rr < 4; ++rr) {
            int s = wq * 16 + q * 4 + rr;
            y[base + (size_t)(t0 + s) * CC + ct * 16 + l15] =
                __float2bfloat16(Y[ct][rr]);
            Mg[cb + (size_t)s * 64 + ct * 16 + l15] = f2bs(M[ct][rr]);
        }
}

// ---------------------------------------------------------------------------
// Pass 2: sequential scan over 32 chunks, elementwise on S[i][j] per (b,h).
// ---------------------------------------------------------------------------
__global__ __launch_bounds__(256) void k_wkv_p2(const short* __restrict__ Mg,
                                                const float* __restrict__ plg,
                                                bf16* __restrict__ Sg)
{
    int bh = blockIdx.x >> 4, part = blockIdx.x & 15;
    int i = part * 4 + (threadIdx.x >> 6), j = threadIdx.x & 63;
    float S = 0.f;
    size_t eb = (size_t)bh * 32 * 4096 + (size_t)i * 64 + j;
    size_t pb = (size_t)bh * 32 * 64 + j;
    for (int c = 0; c < 32; ++c) {
        Sg[eb + (size_t)c * 4096] = __float2bfloat16(S);
        S = plg[pb + (size_t)c * 64] * S + bs2f(Mg[eb + (size_t)c * 4096]);
    }
}

// ---------------------------------------------------------------------------
// Pass 3: gate tile G = hid_g @ gate_w2^T (MFMA, frag-aligned with Y);
// Y = Y_local + RT.S_in (MFMA); fused groupnorm-over-head * G -> A2 bf16.
// ---------------------------------------------------------------------------
__global__ __launch_bounds__(256) void k_wkv_p3(const bf16* __restrict__ RTg,
                                                const bf16* __restrict__ Sg,
                                                const bf16* __restrict__ y,
                                                const bf16* __restrict__ hidG,
                                                const bf16* __restrict__ w2g,
                                                const float* __restrict__ ln_g,
                                                const float* __restrict__ ln_b,
                                                bf16* __restrict__ A2)
{
    constexpr int PB = 72;
    __shared__ __align__(16) short BufA[64 * PB], BufB[64 * PB];
    const int tid = threadIdx.x;
    const int lane = tid & 63, wq = tid >> 6;
    const int l15 = lane & 15, q = lane >> 4;
    const int bh = blockIdx.x >> 5, c = blockIdx.x & 31;
    const int b = bh >> 4, h = bh & 15;
    const int t0 = c * 64;
    const int bt0 = b * TT + t0;
    const size_t cb = (size_t)blockIdx.x * 4096;

    // ---- stage hid_g tile + gate_w2 slice; compute G frags
#pragma unroll
    for (int rnd = 0; rnd < 2; ++rnd) {
        int ee = rnd * 256 + tid;
        int rw = ee >> 3, c8 = (ee & 7) * 8;
        *(bf16x8*)(BufA + rw * PB + c8) =
            *(const bf16x8*)(hidG + (size_t)(bt0 + rw) * 64 + c8);
        *(bf16x8*)(BufB + rw * PB + c8) =
            *(const bf16x8*)(w2g + (size_t)(h * 64 + rw) * 64 + c8);
    }
    __syncthreads();
    f32x4 G[4] = {};
    {
        bf16x8 aH0 = *(const bf16x8*)(BufA + (wq * 16 + l15) * PB + q * 8);
        bf16x8 aH1 = *(const bf16x8*)(BufA + (wq * 16 + l15) * PB + q * 8 + 32);
#pragma unroll
        for (int ct = 0; ct < 4; ++ct) {
            bf16x8 bW0 = *(const bf16x8*)(BufB + (ct * 16 + l15) * PB + q * 8);
            bf16x8 bW1 = *(const bf16x8*)(BufB + (ct * 16 + l15) * PB + q * 8 + 32);
            G[ct] = MFMA(aH0, bW0, G[ct]);
            G[ct] = MFMA(aH1, bW1, G[ct]);
        }
    }
    __syncthreads();
    // ---- stage RT + S_in
#pragma unroll
    for (int rnd = 0; rnd < 2; ++rnd) {
        int ee = rnd * 256 + tid;
        int rw = ee >> 3, c8 = (ee & 7) * 8;
        *(bf16x8*)(BufA + rw * PB + c8) =
            *(const bf16x8*)((const short*)RTg + cb + rw * 64 + c8);
        *(bf16x8*)(BufB + rw * PB + c8) =
            *(const bf16x8*)((const short*)Sg + cb + rw * 64 + c8);
    }
    __syncthreads();

    // preload Y_local into C frags, accumulate cross term on top
    f32x4 Yc[4];
#pragma unroll
    for (int ct = 0; ct < 4; ++ct)
#pragma unroll
        for (int rr = 0; rr < 4; ++rr) {
            int s = wq * 16 + q * 4 + rr;
            Yc[ct][rr] = __bfloat162float(
                y[((size_t)bt0 + s) * CC + h * NN + ct * 16 + l15]);
        }
    bf16x8 aF0 = *(const bf16x8*)(BufA + (wq * 16 + l15) * PB + q * 8);
    bf16x8 aF1 = *(const bf16x8*)(BufA + (wq * 16 + l15) * PB + q * 8 + 32);
#pragma unroll
    for (int ct = 0; ct < 4; ++ct) {
        bf16x8 bS0 = *(const bf16x8*)(BufB + (ct * 16 + l15) * PB + q * 8);
        bf16x8 bS1 = *(const bf16x8*)(BufB + (ct * 16 + l15) * PB + q * 8 + 32);
        Yc[ct] = MFMA(aF0, bS0, Yc[ct]);
        Yc[ct] = MFMA(aF1, bS1, Yc[ct]);
    }
    // groupnorm over the 64 head channels (cols = ct*16+l15) per row s, * G
#pragma unroll
    for (int rr = 0; rr < 4; ++rr) {
        float s1 = 0.f, s2 = 0.f;
#pragma unroll
        for (int ct = 0; ct < 4; ++ct) {
            float vA = Yc[ct][rr];
            s1 += vA; s2 += vA * vA;
        }
#pragma unroll
        for (int o = 1; o < 16; o <<= 1) {
            s1 += __shfl_xor(s1, o);
            s2 += __shfl_xor(s2, o);
        }
        float mu  = s1 * (1.f / 64.f);
        float var = s2 * (1.f / 64.f) - mu * mu;
        float rstd = rsqrtf(var + 6.4e-4f);
        int s = wq * 16 + q * 4 + rr;
        size_t mrow = ((size_t)bt0 + s) * CC;
#pragma unroll
        for (int ct = 0; ct < 4; ++ct) {
            int ch = h * NN + ct * 16 + l15;
            float yn = (Yc[ct][rr] - mu) * rstd;
            float out = (yn * ln_g[ch] + ln_b[ch]) * G[ct][rr];
            A2[mrow + ch] = __float2bfloat16(out);
        }
    }
}

__global__ __launch_bounds__(256) void g_out(const bf16* __restrict__ A2,
                                             const bf16* __restrict__ WoT,
                                             float* __restrict__ out)
{
    __shared__ __align__(16) short lds[8192];
    int m0 = blockIdx.x * 128, n0 = blockIdx.y * 128;
    gemm128(lds, lds + 4096, A2, CC, WoT, CC, CC / 32, m0, n0,
            [&](int m, int n, float v) { out[(size_t)m * CC + n] = v; });
}

// ---------------------------------------------------------------------------
extern "C" void kernel_launch(void* const* d_in, const int* in_sizes, int n_in,
                              void* d_out, int out_size, void* d_ws, size_t ws_size,
                              hipStream_t stream)
{
    const float* x        = (const float*)d_in[0];
    const float* maa_x    = (const float*)d_in[1];
    const float* maa_w    = (const float*)d_in[2];
    const float* maa_k    = (const float*)d_in[3];
    const float* maa_v    = (const float*)d_in[4];
    const float* maa_r    = (const float*)d_in[5];
    const float* maa_g    = (const float*)d_in[6];
    const float* maa_w1   = (const float*)d_in[7];
    const float* maa_w2   = (const float*)d_in[8];
    const float* Wr       = (const float*)d_in[9];
    const float* Wk       = (const float*)d_in[10];
    const float* Wv       = (const float*)d_in[11];
    const float* Wo       = (const float*)d_in[12];
    const float* gate_w1  = (const float*)d_in[13];
    const float* gate_w2  = (const float*)d_in[14];
    const float* time_dec = (const float*)d_in[15];
    const float* decay_w1 = (const float*)d_in[16];
    const float* decay_w2 = (const float*)d_in[17];
    const float* u        = (const float*)d_in[18];
    const float* ln_g     = (const float*)d_in[19];
    const float* ln_b     = (const float*)d_in[20];

    // --- workspace layout with lifetime reuse ---
    size_t off = 0;
    auto alloc = [&](size_t bytes) {
        off = (off + 255) & ~(size_t)255;
        void* p = (char*)d_ws + off;
        off += bytes;
        return p;
    };
    bf16*  WT3   = (bf16*) alloc(3ull * CC * CC * 2);       // WrT,WkT,WvT
    bf16*  WoT   = (bf16*) alloc((size_t)CC * CC * 2);
    bf16*  w1T   = (bf16*) alloc(256ull * CC * 2);          // maa_w1^T padded
    bf16*  w1T2  = (bf16*) alloc(2ull * 128 * CC * 2);      // gate_w1^T, decay_w1^T
    bf16*  w2T2  = (bf16*) alloc(2ull * CC * 64 * 2);       // gate_w2^T, decay_w2^T
    bf16*  w2T5  = (bf16*) alloc(5ull * CC * 32 * 2);       // maa_w2[f]^T
    float* maas  = (float*)alloc(5ull * CC * 4);
    // bufA 16 MB: xxx (dead after g_lora) -> A2 (written by p3)
    char* bufA = (char*)alloc((size_t)BT * CC * 2);
    bf16* xxxbf = (bf16*)bufA;
    bf16* A2    = (bf16*)bufA;
    // bufB 2.56 MB: lora (dead after g_xvar) -> hid (2 MB, lives through p3)
    char* bufB = (char*)alloc((size_t)BT * 160 * 2);
    bf16* Lbf  = (bf16*)bufB;
    bf16* hid  = (bf16*)bufB;
    // bufC 80 MB: xvars (dead after g_rkv5) -> ybuf bf16(16M) | RTg(16.8M)
    char* bufC = (char*)alloc(5ull * BT * CC * 2);
    bf16*  xvars = (bf16*)bufC;
    bf16*  ybuf  = (bf16*)bufC;
    bf16*  RTg   = (bf16*)(bufC + (size_t)BT * CC * 2);
    // bufD 48 MB: r,k,v bf16 (dead after p1) -> S_in bf16 (16.8M, by p2)
    bf16*  rkv  = (bf16*)alloc(3ull * BT * CC * 2);
    bf16*  Sg   = rkv;
    // xb/xxb bf16 packs (16 MB each), Mg bf16 (16.8 MB), pl fp32 (0.5 MB)
    bf16*  xb   = (bf16*) alloc((size_t)BT * CC * 2);
    bf16*  xxb  = (bf16*) alloc((size_t)BT * CC * 2);
    short* Mg   = (short*)alloc(64ull * 32 * 4096 * 2);
    float* plg  = (float*)alloc(64ull * 32 * 64 * 4);

    // --- single fused prep launch (weights + xxx/xb/xxb) ---
    k_prep_all<<<dim3(13092), 256, 0, stream>>>(
        Wr, Wk, Wv, Wo, maa_w1, gate_w1, decay_w1, gate_w2, decay_w2, maa_w2,
        maa_w, maa_k, maa_v, maa_r, maa_g, x, maa_x,
        WT3, WoT, w1T, w1T2, w2T2, w2T5, maas, xxxbf, xb, xxb);

    // --- forward pipeline ---
    g_lora<<<dim3(64, 2), 256, 0, stream>>>(xxxbf, w1T, Lbf);
    g_xvar<<<dim3(64, 8), 256, 0, stream>>>(Lbf, w2T5, maas, xb, xxb, xvars);
    g_rkv5<<<dim3(64, 8, 5), 256, 0, stream>>>(xvars, WT3, w1T2, rkv, hid);
    k_wkv_p1<<<dim3(2048), 256, 0, stream>>>(rkv, rkv + (size_t)BT * CC,
                                             rkv + 2ull * BT * CC,
                                             hid + (size_t)BT * 64,   // hid_w
                                             w2T2 + CC * 64,          // decay_w2^T
                                             time_dec, u, ybuf, RTg, Mg, plg);
    k_wkv_p2<<<dim3(1024), 256, 0, stream>>>(Mg, plg, Sg);
    k_wkv_p3<<<dim3(2048), 256, 0, stream>>>(RTg, Sg, ybuf,
                                             hid,                     // hid_g
                                             w2T2,                    // gate_w2^T
                                             ln_g, ln_b, A2);
    g_out<<<dim3(64, 8), 256, 0, stream>>>(A2, WoT, (float*)d_out);
}

// Round 8
// 418.686 us; speedup vs baseline: 1.1296x; 1.1296x over previous
//
#include <hip/hip_runtime.h>
#include <hip/hip_bf16.h>
#include <stdint.h>

typedef __hip_bfloat16 bf16;
typedef __attribute__((ext_vector_type(8))) short bf16x8;   // 8 bf16 = 4 VGPRs (MFMA A/B frag)
typedef __attribute__((ext_vector_type(4))) float f32x4;    // MFMA C/D frag

#define CC 1024
#define TT 2048
#define BB 4
#define BT 8192     // BB*TT
#define HH 16
#define NN 64       // head size

#define MFMA(a, b, c) __builtin_amdgcn_mfma_f32_16x16x32_bf16(a, b, c, 0, 0, 0)

// async global->LDS, 16B per lane. Direct addrspace casts (addrspacecast),
// NOT via uintptr_t (inttoptr of flat addr -> garbage LDS offset -> fault).
#define GLD(g, l) __builtin_amdgcn_global_load_lds( \
    (const __attribute__((address_space(1))) void*)(g), \
    (__attribute__((address_space(3))) void*)(l), 16, 0, 0)

__device__ __forceinline__ short f2bs(float f) {
    bf16 h = __float2bfloat16(f);
    return *reinterpret_cast<short*>(&h);
}
__device__ __forceinline__ float bs2f(short s) {
    bf16 h = *reinterpret_cast<bf16*>(&s);
    return __bfloat162float(h);
}

// ---------------------------------------------------------------------------
// 128x128 MFMA GEMM core, BK=32 (m97 structure) — used by small-K GEMMs.
// ---------------------------------------------------------------------------
template <typename EPI>
__device__ __forceinline__ void gemm128(short* As, short* Bs,
                                        const bf16* __restrict__ A, int lda,
                                        const bf16* __restrict__ Bt, int ldb,
                                        int kiters, int m0, int n0, EPI epi)
{
    const int tid = threadIdx.x;
    const int l   = tid & 63, wv = tid >> 6;
    const int wm  = wv >> 1, wn = wv & 1;
    const int q   = l >> 4, lr = l & 15;
    const int row = tid & 127, kg1 = tid >> 7;

    f32x4 acc[4][4] = {};

    const bf16* ga = A  + (size_t)(m0 + row) * lda + kg1 * 8;
    const bf16* gb = Bt + (size_t)(n0 + row) * ldb + kg1 * 8;
    short* la1 = As + tid * 8;
    short* la2 = As + (tid + 256) * 8;
    short* lb1 = Bs + tid * 8;
    short* lb2 = Bs + (tid + 256) * 8;

    for (int kb = 0; kb < kiters; ++kb) {
        __syncthreads();
        const bf16* gak = ga + kb * 32;
        const bf16* gbk = gb + kb * 32;
        GLD(gak,      la1);
        GLD(gak + 16, la2);
        GLD(gbk,      lb1);
        GLD(gbk + 16, lb2);
        __syncthreads();
        bf16x8 af[4], bfb[4];
#pragma unroll
        for (int mt = 0; mt < 4; ++mt)
            af[mt] = *(const bf16x8*)(As + (q * 128 + wm * 64 + mt * 16 + lr) * 8);
#pragma unroll
        for (int nt = 0; nt < 4; ++nt)
            bfb[nt] = *(const bf16x8*)(Bs + (q * 128 + wn * 64 + nt * 16 + lr) * 8);
#pragma unroll
        for (int mt = 0; mt < 4; ++mt)
#pragma unroll
            for (int nt = 0; nt < 4; ++nt)
                acc[mt][nt] = MFMA(af[mt], bfb[nt], acc[mt][nt]);
    }
#pragma unroll
    for (int mt = 0; mt < 4; ++mt)
#pragma unroll
        for (int nt = 0; nt < 4; ++nt)
#pragma unroll
            for (int rr = 0; rr < 4; ++rr)
                epi(m0 + wm * 64 + mt * 16 + q * 4 + rr,
                    n0 + wn * 64 + nt * 16 + lr, acc[mt][nt][rr]);
}

// ---------------------------------------------------------------------------
// 128x128 MFMA GEMM core, BK=64: 32 MFMA per barrier-pair. Measured best for
// the K=1024 GEMMs when fused (r6: 137 µs vs r7 BK=32: 165 µs).
// ---------------------------------------------------------------------------
template <typename EPI>
__device__ __forceinline__ void gemm128k64(short* As, short* Bs,
                                           const bf16* __restrict__ A, int lda,
                                           const bf16* __restrict__ Bt, int ldb,
                                           int kiters, int m0, int n0, EPI epi)
{
    const int tid = threadIdx.x;
    const int l   = tid & 63, wv = tid >> 6;
    const int wm  = wv >> 1, wn = wv & 1;
    const int q   = l >> 4, lr = l & 15;
    const int row = tid & 127, kg1 = tid >> 7;

    f32x4 acc[4][4] = {};

    const bf16* ga = A  + (size_t)(m0 + row) * lda + kg1 * 8;
    const bf16* gb = Bt + (size_t)(n0 + row) * ldb + kg1 * 8;

    for (int kb = 0; kb < kiters; ++kb) {
        __syncthreads();
        const bf16* gak = ga + kb * 64;
        const bf16* gbk = gb + kb * 64;
        GLD(gak,      As + tid * 8);
        GLD(gak + 16, As + (tid + 256) * 8);
        GLD(gak + 32, As + (tid + 512) * 8);
        GLD(gak + 48, As + (tid + 768) * 8);
        GLD(gbk,      Bs + tid * 8);
        GLD(gbk + 16, Bs + (tid + 256) * 8);
        GLD(gbk + 32, Bs + (tid + 512) * 8);
        GLD(gbk + 48, Bs + (tid + 768) * 8);
        __syncthreads();
        bf16x8 af[2][4], bfb[2][4];
#pragma unroll
        for (int hh = 0; hh < 2; ++hh) {
#pragma unroll
            for (int mt = 0; mt < 4; ++mt)
                af[hh][mt] = *(const bf16x8*)(As +
                    ((q + hh * 4) * 128 + wm * 64 + mt * 16 + lr) * 8);
#pragma unroll
            for (int nt = 0; nt < 4; ++nt)
                bfb[hh][nt] = *(const bf16x8*)(Bs +
                    ((q + hh * 4) * 128 + wn * 64 + nt * 16 + lr) * 8);
        }
#pragma unroll
        for (int mt = 0; mt < 4; ++mt)
#pragma unroll
            for (int nt = 0; nt < 4; ++nt) {
                acc[mt][nt] = MFMA(af[0][mt], bfb[0][nt], acc[mt][nt]);
                acc[mt][nt] = MFMA(af[1][mt], bfb[1][nt], acc[mt][nt]);
            }
    }
#pragma unroll
    for (int mt = 0; mt < 4; ++mt)
#pragma unroll
        for (int nt = 0; nt < 4; ++nt)
#pragma unroll
            for (int rr = 0; rr < 4; ++rr)
                epi(m0 + wm * 64 + mt * 16 + q * 4 + rr,
                    n0 + wn * 64 + nt * 16 + lr, acc[mt][nt][rr]);
}

// ---------------------------------------------------------------------------
// ALL prep in one launch: 13092 blocks (weights transpose + xxx/xb/xxb).
// ---------------------------------------------------------------------------
__global__ __launch_bounds__(256) void k_prep_all(
    const float* __restrict__ Wr, const float* __restrict__ Wk,
    const float* __restrict__ Wv, const float* __restrict__ Wo,
    const float* __restrict__ maa_w1, const float* __restrict__ gate_w1,
    const float* __restrict__ decay_w1, const float* __restrict__ gate_w2,
    const float* __restrict__ decay_w2, const float* __restrict__ maa_w2,
    const float* __restrict__ mw, const float* __restrict__ mk,
    const float* __restrict__ mv, const float* __restrict__ mr,
    const float* __restrict__ mg, const float* __restrict__ x,
    const float* __restrict__ maa_x,
    bf16* __restrict__ WT3, bf16* __restrict__ WoT, bf16* __restrict__ w1T,
    bf16* __restrict__ w1T2, bf16* __restrict__ w2T2, bf16* __restrict__ w2T5,
    float* __restrict__ maas, bf16* __restrict__ xxx,
    bf16* __restrict__ xb, bf16* __restrict__ xxb)
{
    __shared__ float tile[32][33];
    int idx = blockIdx.x;
    if (idx >= 4900) {                       // xb=x, xxb=shift(x)-x, xxx=x+xx*maa_x
        size_t i = ((size_t)(idx - 4900) * 256 + threadIdx.x) * 4;
        int cc = i & (CC - 1);
        int t  = (i >> 10) & (TT - 1);
        float4 xm = *(const float4*)(x + i);
        float4 xp = t ? *(const float4*)(x + i - CC)
                      : make_float4(0.f, 0.f, 0.f, 0.f);
        float4 ax = *(const float4*)(maa_x + cc);
        float xxv[4] = {xp.x - xm.x, xp.y - xm.y, xp.z - xm.z, xp.w - xm.w};
        float xmv[4] = {xm.x, xm.y, xm.z, xm.w};
        float axv[4] = {ax.x, ax.y, ax.z, ax.w};
#pragma unroll
        for (int e = 0; e < 4; ++e) {
            xb[i + e]  = __float2bfloat16(xmv[e]);
            xxb[i + e] = __float2bfloat16(xxv[e]);
            xxx[i + e] = __float2bfloat16(xmv[e] + xxv[e] * axv[e]);
        }
        return;
    }
    const float* src; bf16* dst; int rows, cols_in, tx_;
    if (idx < 4096) {
        int s = idx >> 10; idx &= 1023;
        src = (s == 0) ? Wr : (s == 1) ? Wk : (s == 2) ? Wv : Wo;
        dst = (s == 3) ? WoT : WT3 + (size_t)s * CC * CC;
        rows = CC; cols_in = CC; tx_ = 32;
    } else if (idx < 4352) { idx -= 4096; src = maa_w1;  dst = w1T;  rows = CC; cols_in = 160; tx_ = 8; }
    else if (idx < 4480)   { idx -= 4352; src = gate_w1; dst = w1T2; rows = CC; cols_in = 64;  tx_ = 4; }
    else if (idx < 4608)   { idx -= 4480; src = decay_w1; dst = w1T2 + 128 * CC; rows = CC; cols_in = 64; tx_ = 4; }
    else if (idx < 4672)   { idx -= 4608; src = gate_w2;  dst = w2T2;           rows = 64; cols_in = CC; tx_ = 32; }
    else if (idx < 4736)   { idx -= 4672; src = decay_w2; dst = w2T2 + CC * 64; rows = 64; cols_in = CC; tx_ = 32; }
    else if (idx < 4896)   { idx -= 4736; int f = idx >> 5; idx &= 31;
                             src = maa_w2 + (size_t)f * 32 * CC;
                             dst = w2T5 + (size_t)f * CC * 32; rows = 32; cols_in = CC; tx_ = 32; }
    else {
        int i = (idx - 4896) * 256 + threadIdx.x;
        if (i < CC) {
            maas[i]          = mw[i];
            maas[CC + i]     = mk[i];
            maas[2 * CC + i] = mv[i];
            maas[3 * CC + i] = mr[i];
            maas[4 * CC + i] = mg[i];
        }
        return;
    }
    int bx = idx % tx_, by = idx / tx_;
    int c0 = bx * 32, r0 = by * 32;
    int tx = threadIdx.x & 31, ty = threadIdx.x >> 5;
    for (int i = ty; i < 32; i += 8) {
        int cc2 = c0 + tx;
        tile[i][tx] = (cc2 < cols_in) ? src[(size_t)(r0 + i) * cols_in + cc2] : 0.f;
    }
    __syncthreads();
    for (int i = ty; i < 32; i += 8)
        dst[(size_t)(c0 + i) * rows + r0 + tx] = __float2bfloat16(tile[tx][i]);
}

__global__ __launch_bounds__(256) void g_lora(const bf16* __restrict__ xxx,
                                              const bf16* __restrict__ w1T,
                                              bf16* __restrict__ L)
{
    __shared__ __align__(16) short lds[8192];
    int m0 = blockIdx.x * 128, n0 = blockIdx.y * 128;
    gemm128(lds, lds + 4096, xxx, CC, w1T, CC, CC / 32, m0, n0,
            [&](int m, int n, float v) {
                if (n < 160) L[(size_t)m * 160 + n] = __float2bfloat16(tanhf(v));
            });
}

// All 5 xvars in one block (f inner loop; xb/xxb bf16 -> half epilogue bytes)
__global__ __launch_bounds__(256) void g_xvar(const bf16* __restrict__ L,
                                              const bf16* __restrict__ w2T,
                                              const float* __restrict__ maas,
                                              const bf16* __restrict__ xb,
                                              const bf16* __restrict__ xxb,
                                              bf16* __restrict__ xvars)
{
    __shared__ __align__(16) short lds[8192];
    int m0 = blockIdx.x * 128, n0 = blockIdx.y * 128;
    for (int f = 0; f < 5; ++f) {
        const bf16* A  = L + f * 32;
        const bf16* Bt = w2T + (size_t)f * CC * 32;
        const float* maa = maas + f * CC;
        bf16* out = xvars + (size_t)f * BT * CC;
        gemm128(lds, lds + 4096, A, 160, Bt, 32, 1, m0, n0,
                [&](int m, int n, float v) {
                    float xm = __bfloat162float(xb[(size_t)m * CC + n]);
                    float xx = __bfloat162float(xxb[(size_t)m * CC + n]);
                    out[(size_t)m * CC + n] =
                        __float2bfloat16(xm + xx * (maa[n] + v));
                });
    }
}

// ---------------------------------------------------------------------------
// r/k/v GEMMs (y<8) + gate/decay hidden GEMMs (y==8, z=0/1) in one dispatch.
// BK=64 core. Grid (64,9,3): hidden blocks interleave EARLY in the dispatch
// stream (x fastest, then y, then z) so they overlap the big GEMMs instead of
// forming a 128-block tail (r6->r7 lesson).
// ---------------------------------------------------------------------------
__global__ __launch_bounds__(256) void g_rkv5(const bf16* __restrict__ xvars,
                                              const bf16* __restrict__ WT,
                                              const bf16* __restrict__ w1T2,
                                              bf16* __restrict__ rkv,
                                              bf16* __restrict__ hid)
{
    __shared__ __align__(16) short lds[16384];
    int z = blockIdx.z;
    int m0 = blockIdx.x * 128;
    if (blockIdx.y < 8) {
        int n0 = blockIdx.y * 128;
        int f = (z == 0) ? 3 : z;              // r<-xr(f3), k<-xk(f1), v<-xv(f2)
        const bf16* A  = xvars + (size_t)f * BT * CC;
        const bf16* Bt = WT + (size_t)z * CC * CC;
        bf16* out = rkv + (size_t)z * BT * CC;
        gemm128k64(lds, lds + 8192, A, CC, Bt, CC, CC / 64, m0, n0,
                   [&](int m, int n, float v) {
                       out[(size_t)m * CC + n] = __float2bfloat16(v);
                   });
    } else {
        if (z == 2) return;
        int zz = z;                            // 0=gate(f4), 1=decay(f0)
        const bf16* A  = xvars + (size_t)(zz == 0 ? 4 : 0) * BT * CC;
        const bf16* Bt = w1T2 + (size_t)zz * 128 * CC;
        bf16* out = hid + (size_t)zz * BT * 64;
        gemm128k64(lds, lds + 8192, A, CC, Bt, CC, CC / 64, m0, 0,
                   [&](int m, int n, float v) {
                       if (n < 64) out[(size_t)m * 64 + n] = __float2bfloat16(tanhf(v));
                   });
    }
}

// ---------------------------------------------------------------------------
// Chunk-parallel WKV6, pass 1: grid 2048 = (bh,chunk), 256 thr / 4 waves.
// Computes its own logw tile: lw[t][j] = -exp(td[ch] + hid_w[t]·w2dec[ch]).
// Then: prefix-scan; build RT,KT,KH,VT; A=tril(RT.KT^T)+diag;
// Y_local = A.V (bf16 out); M = VT.KH^T (bf16 out); RT persisted; pl out.
// ---------------------------------------------------------------------------
__global__ __launch_bounds__(256) void k_wkv_p1(const bf16* __restrict__ r,
                                                const bf16* __restrict__ kk,
                                                const bf16* __restrict__ vv,
                                                const bf16* __restrict__ hidW,
                                                const bf16* __restrict__ w2d,
                                                const float* __restrict__ td,
                                                const float* __restrict__ u,
                                                bf16* __restrict__ y,
                                                bf16* __restrict__ RTg,
                                                short* __restrict__ Mg,
                                                float* __restrict__ plg)
{
    constexpr int PW = 65, PB = 72;
    __shared__ __align__(16) char smem[16640 + 3 * 9216 + 768];
    float* LW = (float*)smem;                          // [64][65] fp32 scan
    short* VT = (short*)smem;                          // [64][72] bf16 (overlay)
    short* RT = (short*)(smem + 16640);                // [64][72]
    short* KT = (short*)(smem + 16640 + 9216);         // [64][72]
    short* AT = KT;                                    // overlay after MFMA1
    short* KH = (short*)(smem + 16640 + 2 * 9216);     // [64][72]
    short* HT = KT;                                    // hid_w staging (pre-C)
    short* WD = KH;                                    // w2dec staging (pre-C)
    float* SU = (float*)(smem + 16640 + 3 * 9216);
    float* SD = SU + 64;

    const int tid = threadIdx.x;
    const int lane = tid & 63, wq = tid >> 6;
    const int row = tid >> 2, g = tid & 3, j0 = g * 16;
    const int l15 = lane & 15, q = lane >> 4;
    const int bh = blockIdx.x >> 5, c = blockIdx.x & 31;
    const int b = bh >> 4, h = bh & 15;
    const size_t base = (size_t)b * TT * CC + (size_t)h * NN;
    const int t0 = c * 64;
    const int bt0 = b * TT + t0;
    const size_t cb = (size_t)blockIdx.x * 4096;       // [bh][c] 64x64 tile base

    if (tid < 64) SU[tid] = u[h * NN + tid];

    // ---- phase A0: stage hid_w tile [64t][64k] and w2dec slice [64ch][64k]
#pragma unroll
    for (int rnd = 0; rnd < 2; ++rnd) {
        int ee = rnd * 256 + tid;
        int rw = ee >> 3, c8 = (ee & 7) * 8;
        *(bf16x8*)(HT + rw * PB + c8) =
            *(const bf16x8*)(hidW + (size_t)(bt0 + rw) * 64 + c8);
        *(bf16x8*)(WD + rw * PB + c8) =
            *(const bf16x8*)(w2d + (size_t)(h * 64 + rw) * 64 + c8);
    }
    // r,k,v loads in flight during the lw MFMA
    const size_t gb = base + (size_t)(t0 + row) * CC + j0;
    bf16x8 r0 = *(const bf16x8*)(r + gb),  r1 = *(const bf16x8*)(r + gb + 8);
    bf16x8 k0 = *(const bf16x8*)(kk + gb), k1 = *(const bf16x8*)(kk + gb + 8);
    bf16x8 v0 = *(const bf16x8*)(vv + gb), v1 = *(const bf16x8*)(vv + gb + 8);
    float tdv[4];
#pragma unroll
    for (int ct = 0; ct < 4; ++ct) tdv[ct] = td[h * 64 + ct * 16 + l15];
    __syncthreads();
    // ---- phase A1: lw tile = hid_w @ w2dec^T ; lw = -exp(td + .)
    {
        bf16x8 aH0 = *(const bf16x8*)(HT + (wq * 16 + l15) * PB + q * 8);
        bf16x8 aH1 = *(const bf16x8*)(HT + (wq * 16 + l15) * PB + q * 8 + 32);
        f32x4 lwa[4] = {};
#pragma unroll
        for (int ct = 0; ct < 4; ++ct) {
            bf16x8 bW0 = *(const bf16x8*)(WD + (ct * 16 + l15) * PB + q * 8);
            bf16x8 bW1 = *(const bf16x8*)(WD + (ct * 16 + l15) * PB + q * 8 + 32);
            lwa[ct] = MFMA(aH0, bW0, lwa[ct]);
            lwa[ct] = MFMA(aH1, bW1, lwa[ct]);
        }
#pragma unroll
        for (int ct = 0; ct < 4; ++ct)
#pragma unroll
            for (int rr = 0; rr < 4; ++rr) {
                int t = wq * 16 + q * 4 + rr, j = ct * 16 + l15;
                LW[t * PW + j] = -expf(tdv[ct] + lwa[ct][rr]);
            }
    }
    __syncthreads();   // LW ready for scan; HT/WD reads done (phase C reuses)
    // ---- phase B: inclusive prefix-sum over t (lane=t), per channel j
    for (int jj = 0; jj < 16; ++jj) {
        int j = wq * 16 + jj;
        float xv = LW[lane * PW + j];
#pragma unroll
        for (int d = 1; d < 64; d <<= 1) {
            float t2 = __shfl_up(xv, d);
            if (lane >= d) xv += t2;
        }
        LW[lane * PW + j] = xv;
    }
    __syncthreads();
    // ---- phase C: build RT, KT, KH, diag, pl
    float rF[16], kF[16];
#pragma unroll
    for (int c2 = 0; c2 < 8; ++c2) {
        rF[c2] = bs2f(r0[c2]); rF[8 + c2] = bs2f(r1[c2]);
        kF[c2] = bs2f(k0[c2]); kF[8 + c2] = bs2f(k1[c2]);
    }
    float cwp[16], cwm[16], cwL[16];
#pragma unroll
    for (int c2 = 0; c2 < 16; ++c2) {
        cwp[c2] = LW[row * PW + j0 + c2];
        cwm[c2] = row ? LW[(row - 1) * PW + j0 + c2] : 0.f;
        cwL[c2] = LW[63 * PW + j0 + c2];
    }
    bf16x8 w0, w1;
#pragma unroll
    for (int c2 = 0; c2 < 8; ++c2) {
        w0[c2] = f2bs(rF[c2] * expf(cwm[c2]));
        w1[c2] = f2bs(rF[8 + c2] * expf(cwm[8 + c2]));
    }
    *(bf16x8*)(RT + row * PB + j0)     = w0;
    *(bf16x8*)(RT + row * PB + j0 + 8) = w1;
    *(bf16x8*)((short*)RTg + cb + row * 64 + j0)     = w0;   // persist for p3
    *(bf16x8*)((short*)RTg + cb + row * 64 + j0 + 8) = w1;
#pragma unroll
    for (int c2 = 0; c2 < 8; ++c2) {
        w0[c2] = f2bs(kF[c2] * expf(-cwp[c2]));
        w1[c2] = f2bs(kF[8 + c2] * expf(-cwp[8 + c2]));
    }
    *(bf16x8*)(KT + row * PB + j0)     = w0;
    *(bf16x8*)(KT + row * PB + j0 + 8) = w1;
#pragma unroll
    for (int c2 = 0; c2 < 16; ++c2)
        KH[(j0 + c2) * PB + row] = f2bs(kF[c2] * expf(cwL[c2] - cwp[c2]));
    if (tid < 64) plg[(size_t)blockIdx.x * 64 + tid] = expf(LW[63 * PW + tid]);
    float dpart = 0.f;
#pragma unroll
    for (int c2 = 0; c2 < 16; ++c2)
        dpart = fmaf(rF[c2] * kF[c2], SU[j0 + c2], dpart);
    dpart += __shfl_xor(dpart, 1);
    dpart += __shfl_xor(dpart, 2);
    if (g == 0) SD[row] = dpart;
    __syncthreads();
    // ---- phase D: VT writes (into dead LW region) + MFMA1 A = RT.KT^T
#pragma unroll
    for (int c2 = 0; c2 < 8; ++c2) {
        VT[(j0 + c2) * PB + row]     = v0[c2];
        VT[(j0 + 8 + c2) * PB + row] = v1[c2];
    }
    bf16x8 aF0 = *(const bf16x8*)(RT + (wq * 16 + l15) * PB + q * 8);
    bf16x8 aF1 = *(const bf16x8*)(RT + (wq * 16 + l15) * PB + q * 8 + 32);
    f32x4 Am[4] = {};
#pragma unroll
    for (int ct = 0; ct < 4; ++ct) {
        bf16x8 bF0 = *(const bf16x8*)(KT + (ct * 16 + l15) * PB + q * 8);
        bf16x8 bF1 = *(const bf16x8*)(KT + (ct * 16 + l15) * PB + q * 8 + 32);
        Am[ct] = MFMA(aF0, bF0, Am[ct]);
        Am[ct] = MFMA(aF1, bF1, Am[ct]);
    }
    __syncthreads();                 // KT reads done -> AT may overlay
#pragma unroll
    for (int ct = 0; ct < 4; ++ct)
#pragma unroll
        for (int rr = 0; rr < 4; ++rr) {
            int s = wq * 16 + q * 4 + rr, p = ct * 16 + l15;
            float vA = Am[ct][rr];
            vA = (p > s) ? 0.f : (p == s ? SD[s] : vA);
            AT[s * PB + p] = f2bs(vA);
        }
    __syncthreads();
    // ---- phase E: Y_local = A.V ; M = VT.KH^T
    f32x4 Y[4] = {}, M[4] = {};
    bf16x8 aA0 = *(const bf16x8*)(AT + (wq * 16 + l15) * PB + q * 8);
    bf16x8 aA1 = *(const bf16x8*)(AT + (wq * 16 + l15) * PB + q * 8 + 32);
    bf16x8 aV0 = *(const bf16x8*)(VT + (wq * 16 + l15) * PB + q * 8);
    bf16x8 aV1 = *(const bf16x8*)(VT + (wq * 16 + l15) * PB + q * 8 + 32);
#pragma unroll
    for (int ct = 0; ct < 4; ++ct) {
        bf16x8 bV0 = *(const bf16x8*)(VT + (ct * 16 + l15) * PB + q * 8);
        bf16x8 bV1 = *(const bf16x8*)(VT + (ct * 16 + l15) * PB + q * 8 + 32);
        Y[ct] = MFMA(aA0, bV0, Y[ct]);
        Y[ct] = MFMA(aA1, bV1, Y[ct]);
        bf16x8 bK0 = *(const bf16x8*)(KH + (ct * 16 + l15) * PB + q * 8);
        bf16x8 bK1 = *(const bf16x8*)(KH + (ct * 16 + l15) * PB + q * 8 + 32);
        M[ct] = MFMA(aV0, bK0, M[ct]);
        M[ct] = MFMA(aV1, bK1, M[ct]);
    }
#pragma unroll
    for (int ct = 0; ct < 4; ++ct)
#pragma unroll
        for (int rr = 0; rr < 4; ++rr) {
            int s = wq * 16 + q * 4 + rr;
            y[base + (size_t)(t0 + s) * CC + ct * 16 + l15] =
                __float2bfloat16(Y[ct][rr]);
            Mg[cb + (size_t)s * 64 + ct * 16 + l15] = f2bs(M[ct][rr]);
        }
}

// ---------------------------------------------------------------------------
// Pass 2: sequential scan over 32 chunks, elementwise on S[i][j] per (b,h).
// ---------------------------------------------------------------------------
__global__ __launch_bounds__(256) void k_wkv_p2(const short* __restrict__ Mg,
                                                const float* __restrict__ plg,
                                                bf16* __restrict__ Sg)
{
    int bh = blockIdx.x >> 4, part = blockIdx.x & 15;
    int i = part * 4 + (threadIdx.x >> 6), j = threadIdx.x & 63;
    float S = 0.f;
    size_t eb = (size_t)bh * 32 * 4096 + (size_t)i * 64 + j;
    size_t pb = (size_t)bh * 32 * 64 + j;
    for (int c = 0; c < 32; ++c) {
        Sg[eb + (size_t)c * 4096] = __float2bfloat16(S);
        S = plg[pb + (size_t)c * 64] * S + bs2f(Mg[eb + (size_t)c * 4096]);
    }
}

// ---------------------------------------------------------------------------
// Pass 3: gate tile G = hid_g @ gate_w2^T (MFMA, frag-aligned with Y);
// Y = Y_local + RT.S_in (MFMA); fused groupnorm-over-head * G -> A2 bf16.
// ---------------------------------------------------------------------------
__global__ __launch_bounds__(256) void k_wkv_p3(const bf16* __restrict__ RTg,
                                                const bf16* __restrict__ Sg,
                                                const bf16* __restrict__ y,
                                                const bf16* __restrict__ hidG,
                                                const bf16* __restrict__ w2g,
                                                const float* __restrict__ ln_g,
                                                const float* __restrict__ ln_b,
                                                bf16* __restrict__ A2)
{
    constexpr int PB = 72;
    __shared__ __align__(16) short BufA[64 * PB], BufB[64 * PB];
    const int tid = threadIdx.x;
    const int lane = tid & 63, wq = tid >> 6;
    const int l15 = lane & 15, q = lane >> 4;
    const int bh = blockIdx.x >> 5, c = blockIdx.x & 31;
    const int b = bh >> 4, h = bh & 15;
    const int t0 = c * 64;
    const int bt0 = b * TT + t0;
    const size_t cb = (size_t)blockIdx.x * 4096;

    // ---- stage hid_g tile + gate_w2 slice; compute G frags
#pragma unroll
    for (int rnd = 0; rnd < 2; ++rnd) {
        int ee = rnd * 256 + tid;
        int rw = ee >> 3, c8 = (ee & 7) * 8;
        *(bf16x8*)(BufA + rw * PB + c8) =
            *(const bf16x8*)(hidG + (size_t)(bt0 + rw) * 64 + c8);
        *(bf16x8*)(BufB + rw * PB + c8) =
            *(const bf16x8*)(w2g + (size_t)(h * 64 + rw) * 64 + c8);
    }
    __syncthreads();
    f32x4 G[4] = {};
    {
        bf16x8 aH0 = *(const bf16x8*)(BufA + (wq * 16 + l15) * PB + q * 8);
        bf16x8 aH1 = *(const bf16x8*)(BufA + (wq * 16 + l15) * PB + q * 8 + 32);
#pragma unroll
        for (int ct = 0; ct < 4; ++ct) {
            bf16x8 bW0 = *(const bf16x8*)(BufB + (ct * 16 + l15) * PB + q * 8);
            bf16x8 bW1 = *(const bf16x8*)(BufB + (ct * 16 + l15) * PB + q * 8 + 32);
            G[ct] = MFMA(aH0, bW0, G[ct]);
            G[ct] = MFMA(aH1, bW1, G[ct]);
        }
    }
    __syncthreads();
    // ---- stage RT + S_in
#pragma unroll
    for (int rnd = 0; rnd < 2; ++rnd) {
        int ee = rnd * 256 + tid;
        int rw = ee >> 3, c8 = (ee & 7) * 8;
        *(bf16x8*)(BufA + rw * PB + c8) =
            *(const bf16x8*)((const short*)RTg + cb + rw * 64 + c8);
        *(bf16x8*)(BufB + rw * PB + c8) =
            *(const bf16x8*)((const short*)Sg + cb + rw * 64 + c8);
    }
    __syncthreads();

    // preload Y_local into C frags, accumulate cross term on top
    f32x4 Yc[4];
#pragma unroll
    for (int ct = 0; ct < 4; ++ct)
#pragma unroll
        for (int rr = 0; rr < 4; ++rr) {
            int s = wq * 16 + q * 4 + rr;
            Yc[ct][rr] = __bfloat162float(
                y[((size_t)bt0 + s) * CC + h * NN + ct * 16 + l15]);
        }
    bf16x8 aF0 = *(const bf16x8*)(BufA + (wq * 16 + l15) * PB + q * 8);
    bf16x8 aF1 = *(const bf16x8*)(BufA + (wq * 16 + l15) * PB + q * 8 + 32);
#pragma unroll
    for (int ct = 0; ct < 4; ++ct) {
        bf16x8 bS0 = *(const bf16x8*)(BufB + (ct * 16 + l15) * PB + q * 8);
        bf16x8 bS1 = *(const bf16x8*)(BufB + (ct * 16 + l15) * PB + q * 8 + 32);
        Yc[ct] = MFMA(aF0, bS0, Yc[ct]);
        Yc[ct] = MFMA(aF1, bS1, Yc[ct]);
    }
    // groupnorm over the 64 head channels (cols = ct*16+l15) per row s, * G
#pragma unroll
    for (int rr = 0; rr < 4; ++rr) {
        float s1 = 0.f, s2 = 0.f;
#pragma unroll
        for (int ct = 0; ct < 4; ++ct) {
            float vA = Yc[ct][rr];
            s1 += vA; s2 += vA * vA;
        }
#pragma unroll
        for (int o = 1; o < 16; o <<= 1) {
            s1 += __shfl_xor(s1, o);
            s2 += __shfl_xor(s2, o);
        }
        float mu  = s1 * (1.f / 64.f);
        float var = s2 * (1.f / 64.f) - mu * mu;
        float rstd = rsqrtf(var + 6.4e-4f);
        int s = wq * 16 + q * 4 + rr;
        size_t mrow = ((size_t)bt0 + s) * CC;
#pragma unroll
        for (int ct = 0; ct < 4; ++ct) {
            int ch = h * NN + ct * 16 + l15;
            float yn = (Yc[ct][rr] - mu) * rstd;
            float out = (yn * ln_g[ch] + ln_b[ch]) * G[ct][rr];
            A2[mrow + ch] = __float2bfloat16(out);
        }
    }
}

__global__ __launch_bounds__(256) void g_out(const bf16* __restrict__ A2,
                                             const bf16* __restrict__ WoT,
                                             float* __restrict__ out)
{
    __shared__ __align__(16) short lds[16384];
    int m0 = blockIdx.x * 128, n0 = blockIdx.y * 128;
    gemm128k64(lds, lds + 8192, A2, CC, WoT, CC, CC / 64, m0, n0,
               [&](int m, int n, float v) { out[(size_t)m * CC + n] = v; });
}

// ---------------------------------------------------------------------------
extern "C" void kernel_launch(void* const* d_in, const int* in_sizes, int n_in,
                              void* d_out, int out_size, void* d_ws, size_t ws_size,
                              hipStream_t stream)
{
    const float* x        = (const float*)d_in[0];
    const float* maa_x    = (const float*)d_in[1];
    const float* maa_w    = (const float*)d_in[2];
    const float* maa_k    = (const float*)d_in[3];
    const float* maa_v    = (const float*)d_in[4];
    const float* maa_r    = (const float*)d_in[5];
    const float* maa_g    = (const float*)d_in[6];
    const float* maa_w1   = (const float*)d_in[7];
    const float* maa_w2   = (const float*)d_in[8];
    const float* Wr       = (const float*)d_in[9];
    const float* Wk       = (const float*)d_in[10];
    const float* Wv       = (const float*)d_in[11];
    const float* Wo       = (const float*)d_in[12];
    const float* gate_w1  = (const float*)d_in[13];
    const float* gate_w2  = (const float*)d_in[14];
    const float* time_dec = (const float*)d_in[15];
    const float* decay_w1 = (const float*)d_in[16];
    const float* decay_w2 = (const float*)d_in[17];
    const float* u        = (const float*)d_in[18];
    const float* ln_g     = (const float*)d_in[19];
    const float* ln_b     = (const float*)d_in[20];

    // --- workspace layout with lifetime reuse ---
    size_t off = 0;
    auto alloc = [&](size_t bytes) {
        off = (off + 255) & ~(size_t)255;
        void* p = (char*)d_ws + off;
        off += bytes;
        return p;
    };
    bf16*  WT3   = (bf16*) alloc(3ull * CC * CC * 2);       // WrT,WkT,WvT
    bf16*  WoT   = (bf16*) alloc((size_t)CC * CC * 2);
    bf16*  w1T   = (bf16*) alloc(256ull * CC * 2);          // maa_w1^T padded
    bf16*  w1T2  = (bf16*) alloc(2ull * 128 * CC * 2);      // gate_w1^T, decay_w1^T
    bf16*  w2T2  = (bf16*) alloc(2ull * CC * 64 * 2);       // gate_w2^T, decay_w2^T
    bf16*  w2T5  = (bf16*) alloc(5ull * CC * 32 * 2);       // maa_w2[f]^T
    float* maas  = (float*)alloc(5ull * CC * 4);
    // bufA 16 MB: xxx (dead after g_lora) -> A2 (written by p3)
    char* bufA = (char*)alloc((size_t)BT * CC * 2);
    bf16* xxxbf = (bf16*)bufA;
    bf16* A2    = (bf16*)bufA;
    // bufB 2.56 MB: lora (dead after g_xvar) -> hid (2 MB, lives through p3)
    char* bufB = (char*)alloc((size_t)BT * 160 * 2);
    bf16* Lbf  = (bf16*)bufB;
    bf16* hid  = (bf16*)bufB;
    // bufC 80 MB: xvars (dead after g_rkv5) -> ybuf bf16(16M) | RTg(16.8M)
    char* bufC = (char*)alloc(5ull * BT * CC * 2);
    bf16*  xvars = (bf16*)bufC;
    bf16*  ybuf  = (bf16*)bufC;
    bf16*  RTg   = (bf16*)(bufC + (size_t)BT * CC * 2);
    // bufD 48 MB: r,k,v bf16 (dead after p1) -> S_in bf16 (16.8M, by p2)
    bf16*  rkv  = (bf16*)alloc(3ull * BT * CC * 2);
    bf16*  Sg   = rkv;
    // xb/xxb bf16 packs (16 MB each), Mg bf16 (16.8 MB), pl fp32 (0.5 MB)
    bf16*  xb   = (bf16*) alloc((size_t)BT * CC * 2);
    bf16*  xxb  = (bf16*) alloc((size_t)BT * CC * 2);
    short* Mg   = (short*)alloc(64ull * 32 * 4096 * 2);
    float* plg  = (float*)alloc(64ull * 32 * 64 * 4);

    // --- single fused prep launch (weights + xxx/xb/xxb) ---
    k_prep_all<<<dim3(13092), 256, 0, stream>>>(
        Wr, Wk, Wv, Wo, maa_w1, gate_w1, decay_w1, gate_w2, decay_w2, maa_w2,
        maa_w, maa_k, maa_v, maa_r, maa_g, x, maa_x,
        WT3, WoT, w1T, w1T2, w2T2, w2T5, maas, xxxbf, xb, xxb);

    // --- forward pipeline ---
    g_lora<<<dim3(64, 2), 256, 0, stream>>>(xxxbf, w1T, Lbf);
    g_xvar<<<dim3(64, 8), 256, 0, stream>>>(Lbf, w2T5, maas, xb, xxb, xvars);
    g_rkv5<<<dim3(64, 9, 3), 256, 0, stream>>>(xvars, WT3, w1T2, rkv, hid);
    k_wkv_p1<<<dim3(2048), 256, 0, stream>>>(rkv, rkv + (size_t)BT * CC,
                                             rkv + 2ull * BT * CC,
                                             hid + (size_t)BT * 64,   // hid_w
                                             w2T2 + CC * 64,          // decay_w2^T
                                             time_dec, u, ybuf, RTg, Mg, plg);
    k_wkv_p2<<<dim3(1024), 256, 0, stream>>>(Mg, plg, Sg);
    k_wkv_p3<<<dim3(2048), 256, 0, stream>>>(RTg, Sg, ybuf,
                                             hid,                     // hid_g
                                             w2T2,                    // gate_w2^T
                                             ln_g, ln_b, A2);
    g_out<<<dim3(64, 8), 256, 0, stream>>>(A2, WoT, (float*)d_out);
}